// Round 3
// baseline (534.242 us; speedup 1.0000x reference)
//
#include <hip/hip_runtime.h>
#include <math.h>

// Problem constants (match reference)
#define BAGS 8
#define NINST 16384
#define DIM 768
#define NCLUST 8
#define NCLASS 2

constexpr int BLOCK = 256;                         // 4 waves
constexpr int WAVES_PER_BLOCK = BLOCK / 64;
constexpr int BLOCKS_PER_BAG = 256;
constexpr int NBLOCKS = BLOCKS_PER_BAG * BAGS;                   // 2048
constexpr int ROWS_PER_BLOCK = NINST / BLOCKS_PER_BAG;           // 64
constexpr int F4_PER_ROW = DIM / 4;                              // 192
constexpr int CHUNK_ROWS = 8;                                    // 24 KB per chunk
constexpr int NCHUNK = ROWS_PER_BLOCK / CHUNK_ROWS;              // 8
constexpr int CHUNK_F4 = CHUNK_ROWS * F4_PER_ROW;                // 1536
constexpr int NCOMP = NCLUST * NCLASS + NCLUST;                  // 24

// async global->LDS DMA, 16 B per lane (global_load_lds_dwordx4).
// HW semantics: per-lane global address, LDS dst = wave-uniform base + lane*16.
// Our layout is exactly lane-contiguous, so this is a straight 24 KB image copy.
__device__ __forceinline__ void load_lds16(const void* g, void* l) {
    __builtin_amdgcn_global_load_lds(
        (const __attribute__((address_space(1))) unsigned int*)g,
        (__attribute__((address_space(3))) unsigned int*)l,
        16, 0, 0);
}

// Stage 1 (m97-style streaming): each block owns 64 contiguous rows of one bag.
// Loop over 8-row chunks: DMA 24 KB global->LDS (6 dwordx4 issues/thread, whole
// chunk in flight), __syncthreads (drains vmcnt), then wave w computes rows
// {2w, 2w+1}: 3 ds_read_b128 per row per lane, dot with preloaded head_w
// fragments, select-accumulate into lane-local acc[cluster][class] (label is
// wave-uniform). ~6 blocks/CU co-resident hide the per-block barrier drains.
// Epilogue: shuffle-reduce, LDS combine across waves, 24 plain stores (NO
// atomics — R1 showed 196K same-line memory-side atomics cost ~700 us).
__global__ __launch_bounds__(BLOCK) void reduce_kernel(
    const float* __restrict__ inst,      // [BAGS, NINST, DIM]
    const int* __restrict__ labels,      // [BAGS, NINST]
    const float* __restrict__ head_w,    // [NCLASS, DIM]
    float* __restrict__ ws)              // [NCOMP, NBLOCKS] component-major
{
    __shared__ float4 buf[CHUNK_F4];                  // 24 KB staging image
    __shared__ int    labs[ROWS_PER_BLOCK];           // labels for our 64 rows
    __shared__ float  lds_s[WAVES_PER_BLOCK][NCLUST * NCLASS];
    __shared__ float  lds_c[WAVES_PER_BLOCK][NCLUST];

    const int bag  = blockIdx.y;
    const int tid  = threadIdx.x;
    const int wave = tid >> 6;
    const int lane = tid & 63;
    const int blockRow0 = blockIdx.x * ROWS_PER_BLOCK;

    if (tid < ROWS_PER_BLOCK)
        labs[tid] = labels[(size_t)bag * NINST + blockRow0 + tid];

    // Preload head_w fragments: lane l owns float4 slots {l, l+64, l+128}.
    const float4* w0p = (const float4*)(head_w);
    const float4* w1p = (const float4*)(head_w + DIM);
    float4 w0[3], w1[3];
#pragma unroll
    for (int i = 0; i < 3; ++i) {
        w0[i] = w0p[lane + i * 64];
        w1[i] = w1p[lane + i * 64];
    }

    float acc0[NCLUST], acc1[NCLUST];
    int cnt[NCLUST];
#pragma unroll
    for (int c = 0; c < NCLUST; ++c) { acc0[c] = 0.f; acc1[c] = 0.f; cnt[c] = 0; }

    const float4* gbase = (const float4*)(inst + (size_t)bag * NINST * DIM)
                        + (size_t)blockRow0 * F4_PER_ROW;

    for (int k = 0; k < NCHUNK; ++k) {
        const float4* src = gbase + (size_t)k * CHUNK_F4;
#pragma unroll
        for (int j = 0; j < CHUNK_F4 / BLOCK; ++j)    // 6 x 4 KB per block
            load_lds16(src + j * BLOCK + tid, &buf[j * BLOCK + tid]);
        __syncthreads();                              // vmcnt(0) drain: chunk staged

#pragma unroll
        for (int r = 0; r < 2; ++r) {
            const int row = wave * 2 + r;                       // within chunk
            const int lab = labs[k * CHUNK_ROWS + row];         // wave-uniform
            float d0 = 0.f, d1 = 0.f;
#pragma unroll
            for (int i = 0; i < 3; ++i) {
                const float4 x = buf[row * F4_PER_ROW + i * 64 + lane];
                d0 = fmaf(x.x, w0[i].x, d0); d0 = fmaf(x.y, w0[i].y, d0);
                d0 = fmaf(x.z, w0[i].z, d0); d0 = fmaf(x.w, w0[i].w, d0);
                d1 = fmaf(x.x, w1[i].x, d1); d1 = fmaf(x.y, w1[i].y, d1);
                d1 = fmaf(x.z, w1[i].z, d1); d1 = fmaf(x.w, w1[i].w, d1);
            }
#pragma unroll
            for (int c = 0; c < NCLUST; ++c) {
                const bool m = (lab == c);
                acc0[c] += m ? d0 : 0.f;
                acc1[c] += m ? d1 : 0.f;
                cnt[c]  += m ? 1 : 0;
            }
        }
        __syncthreads();                              // protect buf before re-stage
    }

    // Wave reduction; counts are wave-uniform (each lane saw the same rows).
#pragma unroll
    for (int c = 0; c < NCLUST; ++c) {
        float a0 = acc0[c], a1 = acc1[c];
#pragma unroll
        for (int off = 32; off >= 1; off >>= 1) {
            a0 += __shfl_down(a0, off, 64);
            a1 += __shfl_down(a1, off, 64);
        }
        if (lane == 0) {
            lds_s[wave][c * 2 + 0] = a0;
            lds_s[wave][c * 2 + 1] = a1;
            lds_c[wave][c] = (float)cnt[c];
        }
    }
    __syncthreads();

    const int bid = blockIdx.y * gridDim.x + blockIdx.x;   // bag*256 + x
    if (tid < NCLUST * NCLASS) {
        const float s = lds_s[0][tid] + lds_s[1][tid] + lds_s[2][tid] + lds_s[3][tid];
        ws[tid * NBLOCKS + bid] = s;
    } else if (tid < NCOMP) {
        const int c = tid - NCLUST * NCLASS;
        const float s = lds_c[0][c] + lds_c[1][c] + lds_c[2][c] + lds_c[3][c];
        ws[tid * NBLOCKS + bid] = s;
    }
}

// One block: threads 0..191 each sum the 256 contiguous partials of one
// (bag, comp) accumulator (float4 loads, L2-resident), then the first 64
// threads do mean-logits, softmax, score = 1 - p[NOR_INDEX=0], argmax over
// clusters (ties -> lowest index, matching jnp.argmax), write winner logits.
__global__ __launch_bounds__(256) void finalize_kernel(
    const float* __restrict__ ws,
    const float* __restrict__ head_b,
    float* __restrict__ out)             // [BAGS, NCLASS]
{
    __shared__ float red[BAGS][NCOMP];
    const int t = threadIdx.x;

    if (t < BAGS * NCOMP) {
        const int bag = t / NCOMP;
        const int comp = t % NCOMP;
        const float4* p = (const float4*)(ws + (size_t)comp * NBLOCKS + bag * BLOCKS_PER_BAG);
        float4 a = make_float4(0.f, 0.f, 0.f, 0.f);
#pragma unroll 4
        for (int i = 0; i < BLOCKS_PER_BAG / 4; ++i) {
            float4 v = p[i];
            a.x += v.x; a.y += v.y; a.z += v.z; a.w += v.w;
        }
        red[bag][comp] = (a.x + a.y) + (a.z + a.w);
    }
    __syncthreads();

    if (t < BAGS * NCLUST) {
        const int bag = t >> 3;
        const int c   = t & 7;

        const float denom = fmaxf(red[bag][NCLUST * NCLASS + c], 1.f);
        const float l0 = red[bag][c * 2 + 0] / denom + head_b[0];
        const float l1 = red[bag][c * 2 + 1] / denom + head_b[1];

        const float m  = fmaxf(l0, l1);
        const float e0 = expf(l0 - m);
        const float e1 = expf(l1 - m);
        const float score = 1.f - e0 / (e0 + e1);

        float bs = score; int bc = c; float bl0 = l0, bl1 = l1;
#pragma unroll
        for (int off = 1; off < 8; off <<= 1) {  // xor 1,2,4 stay in the 8-lane group
            const float os  = __shfl_xor(bs, off, 64);
            const int   oc  = __shfl_xor(bc, off, 64);
            const float ol0 = __shfl_xor(bl0, off, 64);
            const float ol1 = __shfl_xor(bl1, off, 64);
            if (os > bs || (os == bs && oc < bc)) { bs = os; bc = oc; bl0 = ol0; bl1 = ol1; }
        }
        if (c == 0) {
            out[bag * NCLASS + 0] = bl0;
            out[bag * NCLASS + 1] = bl1;
        }
    }
}

extern "C" void kernel_launch(void* const* d_in, const int* in_sizes, int n_in,
                              void* d_out, int out_size, void* d_ws, size_t ws_size,
                              hipStream_t stream) {
    const float* inst   = (const float*)d_in[0];   // [B,N,D] fp32
    const int*   labels = (const int*)d_in[1];     // [B,N] int32
    const float* head_w = (const float*)d_in[2];   // [NC,D] fp32
    const float* head_b = (const float*)d_in[3];   // [NC] fp32
    float* out = (float*)d_out;                    // [B,NC] fp32

    float* ws = (float*)d_ws;   // NCOMP * NBLOCKS floats = 192 KiB; every slot
                                // is written by stage 1 before stage 2 reads it
                                // -> no zero-init needed (0xAA poison is fine).

    dim3 grid(BLOCKS_PER_BAG, BAGS);
    reduce_kernel<<<grid, BLOCK, 0, stream>>>(inst, labels, head_w, ws);
    finalize_kernel<<<1, 256, 0, stream>>>(ws, head_b, out);
}